// Round 2
// baseline (313.963 us; speedup 1.0000x reference)
//
#include <hip/hip_runtime.h>
#include <hip/hip_bf16.h>

// ContrastiveLoss: loss = mean_i [ logsumexp_j(logits[i,:]) - pos_sim[i,i] ]
// logits = [20*xn@tn^T | 20*xn@hn^T + I], rows normalized.
// Round 2: MX-fp8 (e4m3, unit scales) GEMM via mfma_scale_f32_32x32x64_f8f6f4
// (2x MFMA rate vs bf16), XOR-swizzled LDS to kill bank conflicts,
// fused exp-sum epilogue (fixed bias 21 >= max logit), tiny finalize.

#define AS1 __attribute__((address_space(1)))
#define AS3 __attribute__((address_space(3)))

constexpr int N = 4096;
constexpr int D = 1024;            // elements per row; also BYTES per fp8 row
constexpr float TEMP_INV = 20.0f;  // 1/0.05
constexpr float CBIAS = 21.0f;     // >= max possible logit (20*1 + 1)

typedef float f32x16 __attribute__((ext_vector_type(16)));
typedef int i32x4 __attribute__((ext_vector_type(4)));
typedef int i32x8 __attribute__((ext_vector_type(8)));

// One block per row (3*N blocks). 256 threads, 4 floats each (D=1024).
// Output: row-normalized fp8 e4m3, packed 4/u32.
__global__ __launch_bounds__(256) void normalize_kernel(
    const float* __restrict__ in0, const float* __restrict__ in1,
    const float* __restrict__ in2, unsigned int* __restrict__ Abuf,
    unsigned int* __restrict__ Bbuf) {
    const int b = blockIdx.x;
    const int mat = b >> 12;       // 0: input, 1: target, 2: hard_negative
    const int row = b & (N - 1);
    const float* src = (mat == 0) ? in0 : (mat == 1) ? in1 : in2;
    unsigned int* dst = (mat == 0) ? (Abuf + (size_t)row * (D / 4))
                      : (mat == 1) ? (Bbuf + (size_t)row * (D / 4))
                                   : (Bbuf + (size_t)(row + N) * (D / 4));
    const int t = threadIdx.x;
    const float4* s4 = (const float4*)(src + (size_t)row * D);
    float4 v = s4[t];
    float p = v.x * v.x + v.y * v.y + v.z * v.z + v.w * v.w;
    for (int m = 32; m; m >>= 1) p += __shfl_down(p, m);  // 64-lane reduce
    __shared__ float red[4];
    const int lane = t & 63, wave = t >> 6;
    if (lane == 0) red[wave] = p;
    __syncthreads();
    const float sumsq = red[0] + red[1] + red[2] + red[3];
    const float inv = 1.0f / fmaxf(sqrtf(sumsq), 1e-8f);
    unsigned int pk = __builtin_amdgcn_cvt_pk_fp8_f32(v.x * inv, v.y * inv, 0, false);
    pk = __builtin_amdgcn_cvt_pk_fp8_f32(v.z * inv, v.w * inv, pk, true);
    dst[t] = pk;
}

// 128x128 tile, BK=64 (fp8 bytes), 4 waves 2x2, each wave 64x64 via 2x2 of
// 32x32x64 MX-fp8 MFMA with unit scales. A:[N,D] fp8, B:[2N,D] fp8 row-major.
// LDS layout XOR-swizzled at 16B-chunk granularity: phys = log ^ ((row>>1)&3),
// applied on the global-source side of global_load_lds (dest stays
// lane-contiguous as HW requires).
__global__ __launch_bounds__(256) void gemm_lse_kernel(
    const unsigned char* __restrict__ A, const unsigned char* __restrict__ B,
    float* __restrict__ rowsum, float* __restrict__ posdiag) {
    __shared__ __align__(16) char As[128 * 64];  // 8 KiB
    __shared__ __align__(16) char Bs[128 * 64];  // 8 KiB

    const int tid = threadIdx.x;
    const int lane = tid & 63;
    const int wave = tid >> 6;
    const int wr = wave >> 1, wc = wave & 1;
    const int arow = lane & 31;    // row/col within a 32-tile
    const int khalf = lane >> 5;   // which 32-byte K-block this lane holds
    const int rowBase = blockIdx.y * 128;
    const int colBase = blockIdx.x * 128;

    f32x16 acc[2][2];
#pragma unroll
    for (int i = 0; i < 2; ++i)
#pragma unroll
        for (int j = 0; j < 2; ++j)
#pragma unroll
            for (int r = 0; r < 16; ++r) acc[i][j][r] = 0.f;

    // Loop-invariant LDS read offsets (bytes). Frag = 32B = 2 x b128 chunks.
    int aoff[2][2], boff[2][2];
#pragma unroll
    for (int rt = 0; rt < 2; ++rt) {
        const int row = wr * 64 + rt * 32 + arow;
        const int sw = (row >> 1) & 3;
#pragma unroll
        for (int c = 0; c < 2; ++c)
            aoff[rt][c] = row * 64 + ((khalf * 2 + c) ^ sw) * 16;
    }
#pragma unroll
    for (int ct = 0; ct < 2; ++ct) {
        const int col = wc * 64 + ct * 32 + arow;
        const int sw = (col >> 1) & 3;
#pragma unroll
        for (int c = 0; c < 2; ++c)
            boff[ct][c] = col * 64 + ((khalf * 2 + c) ^ sw) * 16;
    }

    // Staging: physical chunk p (16B) at LDS byte p*16; thread t covers p=t
    // and p=t+256. Global source applies the inverse (==same) XOR swizzle.
    const int p0 = tid, p1 = tid + 256;
    const int r0 = p0 >> 2, l0 = (p0 & 3) ^ ((r0 >> 1) & 3);
    const int r1 = p1 >> 2, l1 = (p1 & 3) ^ ((r1 >> 1) & 3);
    const unsigned char* gA0 = A + (size_t)(rowBase + r0) * D + l0 * 16;
    const unsigned char* gA1 = A + (size_t)(rowBase + r1) * D + l1 * 16;
    const unsigned char* gB0 = B + (size_t)(colBase + r0) * D + l0 * 16;
    const unsigned char* gB1 = B + (size_t)(colBase + r1) * D + l1 * 16;

    for (int kb = 0; kb < D / 64; ++kb) {
        const int k0 = kb * 64;
        __syncthreads();  // prior reads done before overwrite
        __builtin_amdgcn_global_load_lds((const AS1 void*)(gA0 + k0),
            (AS3 void*)(As + wave * 1024), 16, 0, 0);
        __builtin_amdgcn_global_load_lds((const AS1 void*)(gA1 + k0),
            (AS3 void*)(As + 4096 + wave * 1024), 16, 0, 0);
        __builtin_amdgcn_global_load_lds((const AS1 void*)(gB0 + k0),
            (AS3 void*)(Bs + wave * 1024), 16, 0, 0);
        __builtin_amdgcn_global_load_lds((const AS1 void*)(gB1 + k0),
            (AS3 void*)(Bs + 4096 + wave * 1024), 16, 0, 0);
        __syncthreads();  // staged data visible

        i32x8 av[2], bv[2];
#pragma unroll
        for (int rt = 0; rt < 2; ++rt) {
            i32x4 lo = *(const i32x4*)(As + aoff[rt][0]);
            i32x4 hi = *(const i32x4*)(As + aoff[rt][1]);
            av[rt] = __builtin_shufflevector(lo, hi, 0, 1, 2, 3, 4, 5, 6, 7);
        }
#pragma unroll
        for (int ct = 0; ct < 2; ++ct) {
            i32x4 lo = *(const i32x4*)(Bs + boff[ct][0]);
            i32x4 hi = *(const i32x4*)(Bs + boff[ct][1]);
            bv[ct] = __builtin_shufflevector(lo, hi, 0, 1, 2, 3, 4, 5, 6, 7);
        }
#pragma unroll
        for (int rt = 0; rt < 2; ++rt)
#pragma unroll
            for (int ct = 0; ct < 2; ++ct)
                acc[rt][ct] = __builtin_amdgcn_mfma_scale_f32_32x32x64_f8f6f4(
                    av[rt], bv[ct], acc[rt][ct],
                    0 /*fmtA=fp8*/, 0 /*fmtB=fp8*/,
                    0, 0x7F7F7F7F, 0, 0x7F7F7F7F /*unit E8M0 scales*/);
    }

    // Epilogue. 32x32 C/D map: col = lane&31, row = (reg&3)+8*(reg>>2)+4*khalf.
#pragma unroll
    for (int rt = 0; rt < 2; ++rt) {
        float rsum[16];
#pragma unroll
        for (int r = 0; r < 16; ++r) rsum[r] = 0.f;
#pragma unroll
        for (int ct = 0; ct < 2; ++ct) {
            const int gcol = colBase + wc * 64 + ct * 32 + arow;
#pragma unroll
            for (int reg = 0; reg < 16; ++reg) {
                const int grow = rowBase + wr * 64 + rt * 32 +
                                 (reg & 3) + 8 * (reg >> 2) + 4 * khalf;
                float logit = acc[rt][ct][reg] * TEMP_INV;
                if (gcol == grow + N) logit += 1.0f;   // hard-negative weight
                if (gcol == grow) posdiag[grow] = logit;  // unique writer
                rsum[reg] += __expf(logit - CBIAS);
            }
        }
#pragma unroll
        for (int reg = 0; reg < 16; ++reg) {
            float v = rsum[reg];
            v += __shfl_xor(v, 1);
            v += __shfl_xor(v, 2);
            v += __shfl_xor(v, 4);
            v += __shfl_xor(v, 8);
            v += __shfl_xor(v, 16);  // stays within 32-lane half
            if (arow == 0) {
                const int grow = rowBase + wr * 64 + rt * 32 +
                                 (reg & 3) + 8 * (reg >> 2) + 4 * khalf;
                atomicAdd(&rowsum[grow], v);
            }
        }
    }
}

__global__ __launch_bounds__(256) void finalize_kernel(
    const float* __restrict__ rowsum, const float* __restrict__ posdiag,
    float* __restrict__ out) {
    const int t = threadIdx.x;
    float s = 0.f;
    for (int i = t; i < N; i += 256)
        s += CBIAS + logf(rowsum[i]) - posdiag[i];
    for (int m = 32; m; m >>= 1) s += __shfl_down(s, m);
    __shared__ float red[4];
    const int lane = t & 63, wave = t >> 6;
    if (lane == 0) red[wave] = s;
    __syncthreads();
    if (t == 0) out[0] = (red[0] + red[1] + red[2] + red[3]) / (float)N;
}

extern "C" void kernel_launch(void* const* d_in, const int* in_sizes, int n_in,
                              void* d_out, int out_size, void* d_ws, size_t ws_size,
                              hipStream_t stream) {
    const float* in0 = (const float*)d_in[0];  // input   [N, D] fp32
    const float* in1 = (const float*)d_in[1];  // target  [N, D] fp32
    const float* in2 = (const float*)d_in[2];  // hardneg [N, D] fp32

    // Workspace: Abuf N*D fp8 (4 MiB) | Bbuf 2N*D fp8 (8 MiB) | rowsum | posdiag
    unsigned char* Abuf = (unsigned char*)d_ws;
    unsigned char* Bbuf = Abuf + (size_t)N * D;
    float* rowsum = (float*)(Bbuf + (size_t)2 * N * D);
    float* posdiag = rowsum + N;

    hipMemsetAsync(rowsum, 0, N * sizeof(float), stream);
    normalize_kernel<<<3 * N, 256, 0, stream>>>(
        in0, in1, in2, (unsigned int*)Abuf, (unsigned int*)Bbuf);
    gemm_lse_kernel<<<dim3(2 * N / 128, N / 128), 256, 0, stream>>>(
        Abuf, Bbuf, rowsum, posdiag);
    finalize_kernel<<<1, 256, 0, stream>>>(rowsum, posdiag, (float*)d_out);
}

// Round 3
// 215.554 us; speedup vs baseline: 1.4565x; 1.4565x over previous
//
#include <hip/hip_runtime.h>
#include <hip/hip_bf16.h>

// ContrastiveLoss: loss = mean_i [ logsumexp_j(logits[i,:]) - pos_sim[i,i] ]
// logits = [20*xn@tn^T | 20*xn@hn^T + I], rows normalized.
// Round 3: back to bf16 MFMA (round-2 MX-fp8 spilled: 256 VGPR, 72MB scratch).
//  - double-buffered LDS K-loop, statically unrolled x2 (4 distinct __shared__
//    arrays) so each barrier's vmcnt(0) drain covers loads issued one full
//    compute phase earlier (round-1 exposed full latency every iter)
//  - XOR-swizzled LDS chunks (phys = quad ^ (row&3)) kills the 4-way
//    ds_read_b128 bank conflict (8.4M conflict cycles in round 1)
//  - normalize: one row per wave, 64B/lane, shfl-only reduce; zeroes rowsum
//    (drops the memset dispatch)

#define AS1 __attribute__((address_space(1)))
#define AS3 __attribute__((address_space(3)))

constexpr int N = 4096;
constexpr int D = 1024;
constexpr float TEMP_INV = 20.0f;  // 1/0.05
constexpr float CBIAS = 21.0f;     // >= max possible logit (20*1 + 1)

typedef float f32x4 __attribute__((ext_vector_type(4)));
typedef short bf16x8 __attribute__((ext_vector_type(8)));

static __device__ __forceinline__ unsigned short f2bf(float f) {
    union { __hip_bfloat16 h; unsigned short u; } cv;
    cv.h = __float2bfloat16(f);  // RNE
    return cv.u;
}

// 3072 blocks x 256. One row per wave (4 rows/block); lane holds 16 floats.
// Blocks 0..15 also zero-init rowsum (16 KiB) so gemm's atomics start clean.
__global__ __launch_bounds__(256) void normalize_kernel(
    const float* __restrict__ in0, const float* __restrict__ in1,
    const float* __restrict__ in2, unsigned short* __restrict__ Abuf,
    unsigned short* __restrict__ Bbuf, float* __restrict__ rowsum) {
    const int t = threadIdx.x, lane = t & 63, wave = t >> 6;
    if (blockIdx.x < 16) rowsum[blockIdx.x * 256 + t] = 0.f;
    const int row = blockIdx.x * 4 + wave;  // 0..12287
    const int mat = row >> 12, r = row & (N - 1);
    const float* src = (mat == 0) ? in0 : (mat == 1) ? in1 : in2;
    unsigned short* dst = (mat == 0) ? (Abuf + (size_t)r * D)
                        : (mat == 1) ? (Bbuf + (size_t)r * D)
                                     : (Bbuf + (size_t)(r + N) * D);
    const float4* s4 = (const float4*)(src + (size_t)r * D);
    float4 v[4];
    float p = 0.f;
#pragma unroll
    for (int j = 0; j < 4; ++j) {
        v[j] = s4[lane + 64 * j];
        p += v[j].x * v[j].x + v[j].y * v[j].y + v[j].z * v[j].z + v[j].w * v[j].w;
    }
#pragma unroll
    for (int m = 1; m < 64; m <<= 1) p += __shfl_xor(p, m);
    const float inv = 1.0f / fmaxf(sqrtf(p), 1e-8f);
    ushort4* d4 = (ushort4*)dst;
#pragma unroll
    for (int j = 0; j < 4; ++j) {
        ushort4 o;
        o.x = f2bf(v[j].x * inv);
        o.y = f2bf(v[j].y * inv);
        o.z = f2bf(v[j].z * inv);
        o.w = f2bf(v[j].w * inv);
        d4[lane + 64 * j] = o;
    }
}

// 128x128 tile, BK=32, 4 waves 2x2, wave 64x64 via 4x4 of 16x16x32 bf16.
// A:[N,D] bf16, B:[2N,D] bf16, row-major. Double-buffered, XOR-swizzled.
__global__ __launch_bounds__(256) void gemm_lse_kernel(
    const unsigned short* __restrict__ A, const unsigned short* __restrict__ B,
    float* __restrict__ rowsum, float* __restrict__ posdiag) {
    __shared__ __align__(16) short As0[128 * 32], Bs0[128 * 32];
    __shared__ __align__(16) short As1[128 * 32], Bs1[128 * 32];

    const int tid = threadIdx.x;
    const int lane = tid & 63;
    const int wave = tid >> 6;
    const int wr = wave >> 1, wc = wave & 1;
    const int quad = lane >> 4, colid = lane & 15;
    const int rowBase = blockIdx.y * 128;
    const int colBase = blockIdx.x * 128;

    f32x4 acc[4][4];
#pragma unroll
    for (int i = 0; i < 4; ++i)
#pragma unroll
        for (int j = 0; j < 4; ++j) acc[i][j] = {0.f, 0.f, 0.f, 0.f};

    // Staging: thread t fills phys 16B-chunks p=t and p=t+256 (LDS byte p*16).
    // phys chunk (r, c): source logical chunk l = c ^ (r & 3)  (self-inverse).
    const int r0 = tid >> 2;                 // 0..63
    const int l0 = (tid & 3) ^ (r0 & 3);     // same for r0+64 (r&3 unchanged)
    const unsigned short* gA0 = A + (size_t)(rowBase + r0) * D + l0 * 8;
    const unsigned short* gA1 = A + (size_t)(rowBase + r0 + 64) * D + l0 * 8;
    const unsigned short* gB0 = B + (size_t)(colBase + r0) * D + l0 * 8;
    const unsigned short* gB1 = B + (size_t)(colBase + r0 + 64) * D + l0 * 8;

    auto issue = [&](short* Asb, short* Bsb, int kb) {
        const int k0 = kb * 32;  // shorts
        __builtin_amdgcn_global_load_lds((const AS1 void*)(gA0 + k0),
            (AS3 void*)(Asb + wave * 512), 16, 0, 0);
        __builtin_amdgcn_global_load_lds((const AS1 void*)(gA1 + k0),
            (AS3 void*)(Asb + 2048 + wave * 512), 16, 0, 0);
        __builtin_amdgcn_global_load_lds((const AS1 void*)(gB0 + k0),
            (AS3 void*)(Bsb + wave * 512), 16, 0, 0);
        __builtin_amdgcn_global_load_lds((const AS1 void*)(gB1 + k0),
            (AS3 void*)(Bsb + 2048 + wave * 512), 16, 0, 0);
    };

    // Loop-invariant frag byte-offsets. Row R's logical chunk q sits at
    // phys = q ^ (R&3). 8 lanes/cycle of a b128 now hit 4 distinct 4-bank
    // groups x2 (2-way = free) instead of 2 groups x4.
    int aoff[4], boff[4];
#pragma unroll
    for (int rt = 0; rt < 4; ++rt) {
        const int R = wr * 64 + rt * 16 + colid;
        aoff[rt] = R * 64 + (quad ^ (R & 3)) * 16;
    }
#pragma unroll
    for (int ct = 0; ct < 4; ++ct) {
        const int C = wc * 64 + ct * 16 + colid;
        boff[ct] = C * 64 + (quad ^ (C & 3)) * 16;
    }

    auto compute = [&](const short* Asb, const short* Bsb) {
        bf16x8 a[4], b[4];
#pragma unroll
        for (int rt = 0; rt < 4; ++rt)
            a[rt] = *(const bf16x8*)((const char*)Asb + aoff[rt]);
#pragma unroll
        for (int ct = 0; ct < 4; ++ct)
            b[ct] = *(const bf16x8*)((const char*)Bsb + boff[ct]);
#pragma unroll
        for (int rt = 0; rt < 4; ++rt)
#pragma unroll
            for (int ct = 0; ct < 4; ++ct)
                acc[rt][ct] = __builtin_amdgcn_mfma_f32_16x16x32_bf16(
                    a[rt], b[ct], acc[rt][ct], 0, 0, 0);
    };

    issue(As0, Bs0, 0);
    for (int kb2 = 0; kb2 < D / 64; ++kb2) {  // 16 pairs = 32 K-steps
        __syncthreads();                       // drains buf0 loads (issued 1 phase ago)
        issue(As1, Bs1, 2 * kb2 + 1);
        compute(As0, Bs0);
        __syncthreads();                       // drains buf1 loads
        if (kb2 + 1 < D / 64) issue(As0, Bs0, 2 * kb2 + 2);
        compute(As1, Bs1);
    }

    // Epilogue: C frag mapping (m89): col = lane&15, row = quad*4 + reg.
#pragma unroll
    for (int rt = 0; rt < 4; ++rt) {
        float rsum[4] = {0.f, 0.f, 0.f, 0.f};
#pragma unroll
        for (int ct = 0; ct < 4; ++ct) {
#pragma unroll
            for (int reg = 0; reg < 4; ++reg) {
                const int grow = rowBase + wr * 64 + rt * 16 + quad * 4 + reg;
                const int gcol = colBase + wc * 64 + ct * 16 + colid;
                float logit = acc[rt][ct][reg] * TEMP_INV;
                if (gcol == grow + N) logit += 1.0f;      // hard-negative weight
                if (gcol == grow) posdiag[grow] = logit;  // unique writer
                rsum[reg] += __expf(logit - CBIAS);
            }
        }
#pragma unroll
        for (int reg = 0; reg < 4; ++reg) {
            float v = rsum[reg];
            v += __shfl_xor(v, 1);
            v += __shfl_xor(v, 2);
            v += __shfl_xor(v, 4);
            v += __shfl_xor(v, 8);
            if (colid == 0) {
                const int grow = rowBase + wr * 64 + rt * 16 + quad * 4 + reg;
                atomicAdd(&rowsum[grow], v);
            }
        }
    }
}

__global__ __launch_bounds__(256) void finalize_kernel(
    const float* __restrict__ rowsum, const float* __restrict__ posdiag,
    float* __restrict__ out) {
    const int t = threadIdx.x;
    float s = 0.f;
    for (int i = t; i < N; i += 256)
        s += CBIAS + logf(rowsum[i]) - posdiag[i];
    for (int m = 32; m; m >>= 1) s += __shfl_down(s, m);
    __shared__ float red[4];
    const int lane = t & 63, wave = t >> 6;
    if (lane == 0) red[wave] = s;
    __syncthreads();
    if (t == 0) out[0] = (red[0] + red[1] + red[2] + red[3]) / (float)N;
}

extern "C" void kernel_launch(void* const* d_in, const int* in_sizes, int n_in,
                              void* d_out, int out_size, void* d_ws, size_t ws_size,
                              hipStream_t stream) {
    const float* in0 = (const float*)d_in[0];  // input   [N, D] fp32
    const float* in1 = (const float*)d_in[1];  // target  [N, D] fp32
    const float* in2 = (const float*)d_in[2];  // hardneg [N, D] fp32

    // Workspace: Abuf N*D bf16 (8 MiB) | Bbuf 2N*D bf16 (16 MiB) | rowsum | posdiag
    unsigned short* Abuf = (unsigned short*)d_ws;
    unsigned short* Bbuf = Abuf + (size_t)N * D;
    float* rowsum = (float*)(Bbuf + (size_t)2 * N * D);
    float* posdiag = rowsum + N;

    normalize_kernel<<<3 * N / 4, 256, 0, stream>>>(in0, in1, in2, Abuf, Bbuf,
                                                    rowsum);
    gemm_lse_kernel<<<dim3(2 * N / 128, N / 128), 256, 0, stream>>>(
        Abuf, Bbuf, rowsum, posdiag);
    finalize_kernel<<<1, 256, 0, stream>>>(rowsum, posdiag, (float*)d_out);
}